// Round 1
// baseline (110.387 us; speedup 1.0000x reference)
//
#include <hip/hip_runtime.h>
#include <hip/hip_bf16.h>

// B=64, M=16, T=2048, L=64, K=32, N=1985
#define B_ 64
#define M_ 16
#define T_ 2048
#define L_ 64
#define K_ 32
#define N_ (T_ - L_ + 1)   // 1985
#define TN 64              // n-positions per block
#define NTH 256            // 4 waves: wave w owns n-subtile [16w,16w+16), both k-tiles
#define NB 4               // batch rows per block: pen tile read once, used 4x
#define MSPLIT 8           // m-phase size (2 phases of 8 m): keeps LDS < 50 KB
#define XROW 144           // per-plane row elems; j<=123 needed. 144 elems = 72 dw
                           // == 8 (mod 32) -> planes at bank offsets {0,8,16,24}:
                           // uniform 4 touches/bank = 512B/wave floor.
#define STSTR 72           // st row stride elems (16B-aligned b128 reads)

typedef __attribute__((ext_vector_type(8))) short bf16x8;
typedef __attribute__((ext_vector_type(4))) float f32x4;

__device__ __forceinline__ unsigned short f2bf(float f) {
    __hip_bfloat16 h = __float2bfloat16(f);
    return __builtin_bit_cast(unsigned short, h);
}

__global__ __launch_bounds__(NTH, 2)
void shapelet_mfma_kernel(const float* __restrict__ x,
                          const float* __restrict__ shp,
                          const float* __restrict__ pmap,
                          unsigned* __restrict__ out) {
    // LDS: 36864 + 4608 + 8192 + 128 = 49792 B -> 2 blocks/CU (grid = 2/CU exactly)
    __shared__ __align__(16) unsigned short xbuf4[NB][MSPLIT][4][XROW];
    __shared__ __align__(16) unsigned short st[K_][STSTR];   // shapelets bf16
    __shared__ __align__(16) float sqw[NB][MSPLIT][TN];      // fp32 sliding sum x^2
    __shared__ float ssb[K_];                                // fp32 sum shp^2

    const int tid = threadIdx.x;
    const int n0 = blockIdx.x * TN;
    const int b0 = blockIdx.y * NB;
    const bool fast = (n0 + 2 * TN <= T_);   // false only for n0=1984

    // ---- one-time: shapelets bf16 + ss fp32 ----
    for (int i = tid; i < K_ * 16; i += NTH) {
        const int k = i >> 4, l4 = (i & 15) * 4;
        float4 v = *(const float4*)(shp + k * L_ + l4);
        ushort4 sv = { f2bf(v.x), f2bf(v.y), f2bf(v.z), f2bf(v.w) };
        *(ushort4*)&st[k][l4] = sv;
    }
    if (tid < K_) {
        float s = 0.f;
        for (int l = 0; l < L_; ++l) { float v = shp[tid * L_ + l]; s = fmaf(v, v, s); }
        ssb[tid] = s;
    }

    // ---- phase staging: x -> 4 shifted bf16 planes + fp32 sliding sum ----
    auto stage = [&](int p) {
        for (int g = tid; g < NB * MSPLIT * 31; g += NTH) {     // 992 items
            const int bb = g / (MSPLIT * 31);
            const int rem = g - bb * (MSPLIT * 31);
            const int mm = rem / 31;
            const int j4 = (rem - mm * 31) * 4;                  // {0,4,...,120}
            const int m = p * MSPLIT + mm;
            const float* src = x + ((size_t)(b0 + bb) * M_ + m) * T_ + n0 + j4;
            float h[8];
            if (fast) {
                float4 v0 = *(const float4*)src;
                float4 v1 = *(const float4*)(src + 4);
                h[0] = v0.x; h[1] = v0.y; h[2] = v0.z; h[3] = v0.w;
                h[4] = v1.x; h[5] = v1.y; h[6] = v1.z; h[7] = v1.w;
            } else {
#pragma unroll
                for (int i = 0; i < 8; ++i)
                    h[i] = (n0 + j4 + i < T_) ? src[i] : 0.f;
            }
            unsigned short hb[8];
#pragma unroll
            for (int i = 0; i < 8; ++i) hb[i] = f2bf(h[i]);
#pragma unroll
            for (int s = 0; s < 4; ++s) {
                ushort4 sv = { hb[s], hb[s + 1], hb[s + 2], hb[s + 3] };
                *(ushort4*)&xbuf4[bb][mm][s][j4] = sv;
            }
        }
        // sqw: 256 threads -> exactly one (bb, mm, j0) window each
        const int bb = tid >> 6, mm = (tid >> 3) & 7, j0 = (tid & 7) * 8;
        const int m = p * MSPLIT + mm;
        const float* xr = x + ((size_t)(b0 + bb) * M_ + m) * T_ + n0;
        float s = 0.f;
        if (fast) {
#pragma unroll
            for (int qd = 0; qd < 16; ++qd) {
                float4 v = *(const float4*)(xr + j0 + qd * 4);
                s = fmaf(v.x, v.x, s); s = fmaf(v.y, v.y, s);
                s = fmaf(v.z, v.z, s); s = fmaf(v.w, v.w, s);
            }
            sqw[bb][mm][j0] = s;
#pragma unroll
            for (int d = 1; d < 8; ++d) {
                float a = xr[j0 + d + L_ - 1], r = xr[j0 + d - 1];
                s += a * a - r * r;
                sqw[bb][mm][j0 + d] = s;
            }
        } else {
            for (int l = 0; l < L_; ++l) {
                float v = (n0 + j0 + l < T_) ? xr[j0 + l] : 0.f;
                s = fmaf(v, v, s);
            }
            sqw[bb][mm][j0] = s;
            for (int d = 1; d < 8; ++d) {
                float a = (n0 + j0 + d + L_ - 1 < T_) ? xr[j0 + d + L_ - 1] : 0.f;
                float r = (n0 + j0 + d - 1 < T_) ? xr[j0 + d - 1] : 0.f;
                s += a * a - r * r;
                sqw[bb][mm][j0 + d] = s;
            }
        }
    };

    stage(0);
    __syncthreads();

    // ---- per-lane MFMA coordinates (proven layout) ----
    const int lane = tid & 63;
    const int w  = tid >> 6;       // wave -> n-subtile [16w, 16w+16)
    const int rl = lane & 15;      // A-row (n within subtile) / B-col (k)
    const int q  = lane >> 4;      // quad
    const int sp = rl & 3;                          // shift plane
    const int e0 = 16 * w + 8 * q + (rl & ~3);      // 4-aligned elem base (max 84)
    const int eq = e0 >> 2;                         // uint2 index (max 21; +9 fits)
    const int nrow = n0 + 16 * w + 4 * q;           // lane's 4 output rows: nrow + reg

    bf16x8 bfr[2][2];
#pragma unroll
    for (int t = 0; t < 2; ++t)
#pragma unroll
        for (int h = 0; h < 2; ++h)
            bfr[t][h] = *(const bf16x8*)&st[16 * t + rl][8 * q + 32 * h];

    const float ssk0 = ssb[rl], ssk1 = ssb[16 + rl];

    const float* pr0 = pmap + (size_t)rl * (M_ * N_) + nrow;   // k = rl
    const float* pr1 = pr0 + (size_t)16 * M_ * N_;             // k = rl + 16

    f32x4 wd0[NB], wd1[NB];
#pragma unroll
    for (int bb = 0; bb < NB; ++bb) { wd0[bb] = (f32x4)0.f; wd1[bb] = (f32x4)0.f; }
    f32x4 P0 = (f32x4)0.f, P1 = (f32x4)0.f;   // sum_m pen (ss folded at the end)
    const f32x4 zero = (f32x4)0.f;

    for (int p = 0; p < 2; ++p) {
        if (p) {
            __syncthreads();
            stage(1);
            __syncthreads();
        }
#pragma unroll 2
        for (int mm = 0; mm < MSPLIT; ++mm) {
            const int m = p * MSPLIT + mm;
            // ---- pmap fp32 for this m, elu inline (no precomputed pen) ----
            float4 pm0, pm1;
            if (fast) {
                pm0 = *(const float4*)(pr0 + (size_t)m * N_);
                pm1 = *(const float4*)(pr1 + (size_t)m * N_);
            } else {
                pm0 = make_float4(0.f, 0.f, 0.f, 0.f);   // masked at the min
                pm1 = make_float4(0.f, 0.f, 0.f, 0.f);
                const float* r0_ = pr0 + (size_t)m * N_;
                const float* r1_ = pr1 + (size_t)m * N_;
                if (nrow     < N_) { pm0.x = r0_[0]; pm1.x = r1_[0]; }
                if (nrow + 1 < N_) { pm0.y = r0_[1]; pm1.y = r1_[1]; }
                if (nrow + 2 < N_) { pm0.z = r0_[2]; pm1.z = r1_[2]; }
                if (nrow + 3 < N_) { pm0.w = r0_[3]; pm1.w = r1_[3]; }
            }
            float pe0[4], pe1[4];
            {
                const float pv0[4] = { pm0.x, pm0.y, pm0.z, pm0.w };
                const float pv1[4] = { pm1.x, pm1.y, pm1.z, pm1.w };
#pragma unroll
                for (int r = 0; r < 4; ++r) {
                    pe0[r] = (pv0[r] < 0.f) ? (2.f - pv0[r]) : (__expf(-pv0[r]) + 1.f);
                    pe1[r] = (pv1[r] < 0.f) ? (2.f - pv1[r]) : (__expf(-pv1[r]) + 1.f);
                    P0[r] += pe0[r];
                    P1[r] += pe1[r];
                }
            }
            // ---- NB batch rows share this pen: 4x MFMA chains per pen load ----
#pragma unroll
            for (int bb = 0; bb < NB; ++bb) {
                const uint2* prow = (const uint2*)&xbuf4[bb][mm][sp][0];
                uint2 lo0 = prow[eq],     hi0 = prow[eq + 1];
                uint2 lo1 = prow[eq + 8], hi1 = prow[eq + 9];
                union { uint2 u2[2]; bf16x8 v; } fa0, fa1;
                fa0.u2[0] = lo0; fa0.u2[1] = hi0;
                fa1.u2[0] = lo1; fa1.u2[1] = hi1;

                f32x4 c0_ = __builtin_amdgcn_mfma_f32_16x16x32_bf16(fa0.v, bfr[0][0], zero, 0, 0, 0);
                c0_       = __builtin_amdgcn_mfma_f32_16x16x32_bf16(fa1.v, bfr[0][1], c0_, 0, 0, 0);
                f32x4 c1_ = __builtin_amdgcn_mfma_f32_16x16x32_bf16(fa0.v, bfr[1][0], zero, 0, 0, 0);
                c1_       = __builtin_amdgcn_mfma_f32_16x16x32_bf16(fa1.v, bfr[1][1], c1_, 0, 0, 0);

                f32x4 sq = *(const f32x4*)&sqw[bb][mm][16 * w + 4 * q];
#pragma unroll
                for (int r = 0; r < 4; ++r) {
                    float u0 = fmaf(-2.f, c0_[r], sq[r]);
                    wd0[bb][r] = fmaf(pe0[r], u0, wd0[bb][r]);
                    float u1 = fmaf(-2.f, c1_[r], sq[r]);
                    wd1[bb][r] = fmaf(pe1[r], u1, wd1[bb][r]);
                }
            }
        }
    }

    // ---- fold ss term: wd += ss_k * sum_m pen ----
#pragma unroll
    for (int bb = 0; bb < NB; ++bb)
#pragma unroll
        for (int r = 0; r < 4; ++r) {
            wd0[bb][r] = fmaf(ssk0, P0[r], wd0[bb][r]);
            wd1[bb][r] = fmaf(ssk1, P1[r], wd1[bb][r]);
        }

    // ---- min: 4 rows -> quads -> LDS cross-wave -> 1 atomic per (b,k) ----
    __syncthreads();
    float* red = (float*)&sqw[0][0][0];   // [4 waves][NB*32 = 128]
#pragma unroll
    for (int bb = 0; bb < NB; ++bb) {
#pragma unroll
        for (int t = 0; t < 2; ++t) {
            float lmin = __int_as_float(0x7F800000);
            const f32x4 wdv = t ? wd1[bb] : wd0[bb];
#pragma unroll
            for (int r = 0; r < 4; ++r)
                if (nrow + r < N_) lmin = fminf(lmin, wdv[r]);
            lmin = fminf(lmin, __shfl_xor(lmin, 16));
            lmin = fminf(lmin, __shfl_xor(lmin, 32));
            if (q == 0) red[w * 128 + bb * 32 + t * 16 + rl] = lmin;
        }
    }
    __syncthreads();
    if (tid < 128) {
        float v = fminf(fminf(red[tid], red[128 + tid]),
                        fminf(red[256 + tid], red[384 + tid]));
        const int bb = tid >> 5, kk = tid & 31;
        atomicMin(out + (size_t)(b0 + bb) * K_ + kk, __float_as_uint(fmaxf(v, 0.f)));
    }
}

extern "C" void kernel_launch(void* const* d_in, const int* in_sizes, int n_in,
                              void* d_out, int out_size, void* d_ws, size_t ws_size,
                              hipStream_t stream) {
    const float* x    = (const float*)d_in[0];   // (B, M, T)
    const float* shp  = (const float*)d_in[1];   // (K, L)
    const float* pmap = (const float*)d_in[2];   // (K, M, N)
    unsigned* out = (unsigned*)d_out;            // (B, K) float bits
    (void)d_ws; (void)ws_size;                   // no workspace: pen computed inline

    // out = 0xFFFFFFFF (> any non-negative float's bits) for atomicMin
    hipMemsetAsync(d_out, 0xFF, (size_t)B_ * K_ * sizeof(unsigned), stream);

    dim3 grid((N_ + TN - 1) / TN, B_ / NB);      // 32 x 16 = 512 blocks = 2/CU
    shapelet_mfma_kernel<<<grid, dim3(NTH), 0, stream>>>(x, shp, pmap, out);
}